// Round 6
// baseline (2675.470 us; speedup 1.0000x reference)
//
#include <hip/hip_runtime.h>

#define HDIM 64
#define BATCH 256
#define TLEN 2048
#define CH 32   // layer-2 streaming chunk (steps)

__device__ __forceinline__ float rcp_fast(float x) { return __builtin_amdgcn_rcpf(x); }
__device__ __forceinline__ float sigmoid_fast(float x) { return rcp_fast(1.0f + __expf(-x)); }
__device__ __forceinline__ float tanh_fast(float x)    { return 1.0f - 2.0f * rcp_fast(1.0f + __expf(2.0f * x)); }

// ---- cross-lane primitives: ALL verified in passing rounds r2-r4 ----
__device__ __forceinline__ float dpp_xor1_add(float x) {   // lane^1 pair sum (quad_perm)
    int v = __builtin_amdgcn_update_dpp(0, __float_as_int(x), 0xB1, 0xF, 0xF, true);
    return x + __int_as_float(v);
}
__device__ __forceinline__ float dpp_xor2_add(float x) {   // lane^2 pair sum (quad_perm)
    int v = __builtin_amdgcn_update_dpp(0, __float_as_int(x), 0x4E, 0xF, 0xF, true);
    return x + __int_as_float(v);
}
__device__ __forceinline__ float swz_xor4_add(float x) {   // lane^4 sum (ds_swizzle)
    int v = __builtin_amdgcn_ds_swizzle(__float_as_int(x), 0x101F);
    return x + __int_as_float(v);
}
__device__ __forceinline__ float dot4(float4 a, float4 b, float acc) {
    acc = fmaf(a.x, b.x, acc); acc = fmaf(a.y, b.y, acc);
    acc = fmaf(a.z, b.z, acc); acc = fmaf(a.w, b.w, acc);
    return acc;
}

// Transparent epilogue. Lane (quad position q) holds the fully-reduced
// preactivation of gate q (order i,f,g,o). Each lane applies ONE activation
// (tanh for q==2, sigmoid otherwise), activated values are exchanged with
// 3 shuffles, then positionally reassembled with 8 selects (mapping verified
// for all q by enumeration). All lanes of a quad end with identical
// (i,f,g,o,c) -> c stays lane-synchronized exactly.
__device__ __forceinline__ float cell_epilogue(float G, float c, int q, float* hout) {
    const float act = (q == 2) ? tanh_fast(G) : sigmoid_fast(G);
    const float a1 = __shfl_xor(act, 1, 64);   // gate q^1's activated value
    const float a2 = __shfl_xor(act, 2, 64);   // gate q^2
    const float a3 = __shfl_xor(act, 3, 64);   // gate q^3
    const bool qb0 = (q & 1), qb1 = (q & 2);
    const float pe = qb0 ? a1 : act, po = qb0 ? act : a1;   // my pair: even,odd gate
    const float oe = qb0 ? a3 : a2,  oo = qb0 ? a2 : a3;    // other pair
    const float gi = qb1 ? oe : pe,  gf = qb1 ? oo : po;    // sigma(i), sigma(f)
    const float gg = qb1 ? pe : oe,  go = qb1 ? po : oo;    // tanh(g~), sigma(o)
    const float cn = fmaf(gf, c, gi * gg);
    *hout = go * tanh_fast(cn);
    return cn;
}

// ---------------- Layer 1: bidirectional, input dim 4 ----------------
// grid = 2*BATCH blocks, 512 threads (8 waves; 2 blocks/CU -> 4 waves/SIMD).
// u = tid>>3 owns hidden unit; L = tid&7 owns h-slice [8L,8L+8); q = L&3 is
// the lane's gate after the pick. 37 weight floats/lane (register-resident).
__global__ __launch_bounds__(512, 4)
void lstm_layer1(const float* __restrict__ x,      // [B,T,4]
                 const float* __restrict__ Wih_f, const float* __restrict__ Whh_f, const float* __restrict__ b_f,
                 const float* __restrict__ Wih_b, const float* __restrict__ Whh_b, const float* __restrict__ b_b,
                 float* __restrict__ out1)         // [B,T,2H]
{
    const int bidx = blockIdx.x >> 1;
    const int dir  = blockIdx.x & 1;
    const float* __restrict__ Wih = dir ? Wih_b : Wih_f;
    const float* __restrict__ Whh = dir ? Whh_b : Whh_f;
    const float* __restrict__ bb  = dir ? b_b   : b_f;

    const int tid = threadIdx.x;
    const int u   = tid >> 3;
    const int L   = tid & 7;
    const int q   = L & 3;

    __shared__ float xlds[TLEN * 4];    // 32 KB
    __shared__ float hbuf[2][HDIM];

    {   // preload x[b] (2048 float4)
        const float4* src = (const float4*)(x + (size_t)bidx * TLEN * 4);
        float4* dst = (float4*)xlds;
        #pragma unroll
        for (int i = 0; i < 4; ++i) dst[tid + 512 * i] = src[tid + 512 * i];
    }
    if (tid < 2 * HDIM) ((float*)hbuf)[tid] = 0.f;

    // h-dot weights: gate g row (g*64+u), cols [8L, 8L+8)
    const float* wbase = Whh + (size_t)u * HDIM + 8 * L;
    const float4 W0a = *(const float4*)(wbase + 0*4096 + 0), W0b = *(const float4*)(wbase + 0*4096 + 4);
    const float4 W1a = *(const float4*)(wbase + 1*4096 + 0), W1b = *(const float4*)(wbase + 1*4096 + 4);
    const float4 W2a = *(const float4*)(wbase + 2*4096 + 0), W2b = *(const float4*)(wbase + 2*4096 + 4);
    const float4 W3a = *(const float4*)(wbase + 3*4096 + 0), W3b = *(const float4*)(wbase + 3*4096 + 4);
    // x weights + bias for this lane's gate only (applied post-reduction)
    const float4 Iq = *(const float4*)(Wih + (size_t)(q * 64 + u) * 4);
    const float  bq = bb[q * 64 + u];
    __syncthreads();

    float c = 0.f;
    const float* xp = xlds + (dir ? (TLEN - 1) * 4 : 0);
    const int xstep = dir ? -4 : 4;
    float* outp = out1 + (size_t)bidx * TLEN * (2 * HDIM)
                + (size_t)(dir ? (TLEN - 1) : 0) * (2 * HDIM) + dir * HDIM + u;
    const ptrdiff_t ostep = dir ? -(2 * HDIM) : (2 * HDIM);

    #pragma unroll 2
    for (int s = 0; s < TLEN; ++s) {
        const float* hb = hbuf[s & 1];
        const float4 h0 = *(const float4*)(hb + 8 * L + 0);
        const float4 h1 = *(const float4*)(hb + 8 * L + 4);

        float p0 = dot4(W0b, h1, dot4(W0a, h0, 0.f));
        float p1 = dot4(W1b, h1, dot4(W1a, h0, 0.f));
        float p2 = dot4(W2b, h1, dot4(W2a, h0, 0.f));
        float p3 = dot4(W3b, h1, dot4(W3a, h0, 0.f));

        // quad all-gather per gate (r4-proven), then pick own gate, then
        // cross-quad sum (r4-proven swizzle).
        p0 = dpp_xor2_add(dpp_xor1_add(p0));
        p1 = dpp_xor2_add(dpp_xor1_add(p1));
        p2 = dpp_xor2_add(dpp_xor1_add(p2));
        p3 = dpp_xor2_add(dpp_xor1_add(p3));
        float G = (q == 0) ? p0 : (q == 1) ? p1 : (q == 2) ? p2 : p3;
        G = swz_xor4_add(G);

        const float4 xv = *(const float4*)xp;
        G = dot4(Iq, xv, G + bq);

        float h;
        c = cell_epilogue(G, c, q, &h);

        if (L == 3) {
            hbuf[(s & 1) ^ 1][u] = h;
            *outp = h;
        }
        outp += ostep;
        xp   += xstep;
        __syncthreads();
    }
}

// ---------------- Layer 2: unidirectional, input dim 128, + FC ----------------
// grid = BATCH blocks, 1024 threads (16 waves; 1 block/CU -> 4 waves/SIMD).
// u = tid>>4 owns unit; L = tid&15 owns x-slice [8L,8L+8) + h-slice [4L,4L+4);
// q = L&3 is the lane's gate after the pick. 48 weight floats/lane.
// Plain [CH][128] x staging (r4 measured zero bank conflicts on such strides).
__global__ __launch_bounds__(1024, 4)
void lstm_layer2(const float* __restrict__ out1,  // [B,T,128]
                 const float* __restrict__ Wih2, const float* __restrict__ Whh2, const float* __restrict__ bias2,
                 const float* __restrict__ Wfc, const float* __restrict__ bfc,
                 float* __restrict__ out)         // [B,1]
{
    const int bidx = blockIdx.x;
    const int tid  = threadIdx.x;
    const int u    = tid >> 4;
    const int L    = tid & 15;
    const int q    = L & 3;

    __shared__ float xbuf[2][CH][2 * HDIM];   // 32 KB
    __shared__ float hbuf[2][HDIM];

    // h-dot weights: gate g row (g*64+u), cols [4L, 4L+4)
    const float* whbase = Whh2 + (size_t)u * HDIM + 4 * L;
    const float4 H0 = *(const float4*)(whbase + 0*4096);
    const float4 H1 = *(const float4*)(whbase + 1*4096);
    const float4 H2 = *(const float4*)(whbase + 2*4096);
    const float4 H3 = *(const float4*)(whbase + 3*4096);
    // x-dot weights: gate g row, cols [8L, 8L+8)
    const float* wibase = Wih2 + (size_t)u * 128 + 8 * L;
    const float4 X0a = *(const float4*)(wibase + 0*8192 + 0), X0b = *(const float4*)(wibase + 0*8192 + 4);
    const float4 X1a = *(const float4*)(wibase + 1*8192 + 0), X1b = *(const float4*)(wibase + 1*8192 + 4);
    const float4 X2a = *(const float4*)(wibase + 2*8192 + 0), X2b = *(const float4*)(wibase + 2*8192 + 4);
    const float4 X3a = *(const float4*)(wibase + 3*8192 + 0), X3b = *(const float4*)(wibase + 3*8192 + 4);
    const float bq = bias2[q * 64 + u];

    if (tid < 2 * HDIM) ((float*)hbuf)[tid] = 0.f;

    const float4* src = (const float4*)(out1 + (size_t)bidx * TLEN * (2 * HDIM));
    ((float4*)&xbuf[0][0][0])[tid] = src[tid];   // stage chunk 0 (1024 float4)
    __syncthreads();

    float c = 0.f;

    for (int chunk = 0; chunk < TLEN / CH; ++chunk) {
        const int cb = chunk & 1;
        const bool havenext = (chunk + 1 < TLEN / CH);
        float4 pf;
        if (havenext) pf = src[(size_t)(chunk + 1) * 1024 + tid];

        #pragma unroll 2
        for (int ts = 0; ts < CH; ++ts) {
            const int s = chunk * CH + ts;
            const float* hb = hbuf[s & 1];
            const float* xr = &xbuf[cb][ts][8 * L];

            const float4 x0 = *(const float4*)(xr + 0);
            const float4 x1 = *(const float4*)(xr + 4);
            const float4 hv = *(const float4*)(hb + 4 * L);

            float p0 = dot4(H0, hv, dot4(X0b, x1, dot4(X0a, x0, 0.f)));
            float p1 = dot4(H1, hv, dot4(X1b, x1, dot4(X1a, x0, 0.f)));
            float p2 = dot4(H2, hv, dot4(X2b, x1, dot4(X2a, x0, 0.f)));
            float p3 = dot4(H3, hv, dot4(X3b, x1, dot4(X3a, x0, 0.f)));

            p0 = dpp_xor2_add(dpp_xor1_add(p0));
            p1 = dpp_xor2_add(dpp_xor1_add(p1));
            p2 = dpp_xor2_add(dpp_xor1_add(p2));
            p3 = dpp_xor2_add(dpp_xor1_add(p3));
            float G = (q == 0) ? p0 : (q == 1) ? p1 : (q == 2) ? p2 : p3;
            G = swz_xor4_add(G);
            G += __shfl_xor(G, 8, 64);
            G += bq;

            float h;
            c = cell_epilogue(G, c, q, &h);

            if (L == 3) hbuf[(s & 1) ^ 1][u] = h;
            __syncthreads();
        }
        if (havenext) {
            ((float4*)&xbuf[cb ^ 1][0][0])[tid] = pf;
            __syncthreads();
        }
    }

    // final h (T even -> hbuf[0]); FC
    if (tid < 64) {
        float part = hbuf[0][tid] * Wfc[tid];
        #pragma unroll
        for (int m = 1; m < 64; m <<= 1) part += __shfl_xor(part, m, 64);
        if (tid == 0) out[bidx] = part + bfc[0];
    }
}

extern "C" void kernel_launch(void* const* d_in, const int* in_sizes, int n_in,
                              void* d_out, int out_size, void* d_ws, size_t ws_size,
                              hipStream_t stream) {
    const float* x     = (const float*)d_in[0];
    const float* Wih_f = (const float*)d_in[1];
    const float* Whh_f = (const float*)d_in[2];
    const float* b_f   = (const float*)d_in[3];
    const float* Wih_b = (const float*)d_in[4];
    const float* Whh_b = (const float*)d_in[5];
    const float* b_b   = (const float*)d_in[6];
    const float* Wih2  = (const float*)d_in[7];
    const float* Whh2  = (const float*)d_in[8];
    const float* b2    = (const float*)d_in[9];
    const float* Wfc   = (const float*)d_in[10];
    const float* bfc   = (const float*)d_in[11];

    float* out1 = (float*)d_ws;  // [B,T,2H] fp32 (268 MB workspace; proven available)

    lstm_layer1<<<dim3(2 * BATCH), dim3(512), 0, stream>>>(
        x, Wih_f, Whh_f, b_f, Wih_b, Whh_b, b_b, out1);
    lstm_layer2<<<dim3(BATCH), dim3(1024), 0, stream>>>(
        out1, Wih2, Whh2, b2, Wfc, bfc, (float*)d_out);
}

// Round 7
// 2372.519 us; speedup vs baseline: 1.1277x; 1.1277x over previous
//
#include <hip/hip_runtime.h>

#define HDIM 64
#define BATCH 256
#define TLEN 2048
#define CH 16   // layer-2 streaming chunk (steps)

__device__ __forceinline__ float rcp_fast(float x) { return __builtin_amdgcn_rcpf(x); }
__device__ __forceinline__ float sigmoid_fast(float x) { return rcp_fast(1.0f + __expf(-x)); }
__device__ __forceinline__ float tanh_fast(float x)    { return 1.0f - 2.0f * rcp_fast(1.0f + __expf(2.0f * x)); }

// quad_perm DPP adds: lane^1 and lane^2 (VALU, no LDS pipe) — r2-r4 proven
__device__ __forceinline__ float dpp_xor1_add(float x) {
    int v = __builtin_amdgcn_update_dpp(0, __float_as_int(x), 0xB1, 0xF, 0xF, true);
    return x + __int_as_float(v);
}
__device__ __forceinline__ float dpp_xor2_add(float x) {
    int v = __builtin_amdgcn_update_dpp(0, __float_as_int(x), 0x4E, 0xF, 0xF, true);
    return x + __int_as_float(v);
}
__device__ __forceinline__ float swz_xor4_add(float x) {
    int v = __builtin_amdgcn_ds_swizzle(__float_as_int(x), 0x101F); // xor-4 butterfly
    return x + __int_as_float(v);
}
__device__ __forceinline__ float dot4(float4 a, float4 b, float acc) {
    acc = fmaf(a.x, b.x, acc); acc = fmaf(a.y, b.y, acc);
    acc = fmaf(a.z, b.z, acc); acc = fmaf(a.w, b.w, acc);
    return acc;
}

// ---- Arm A (compiler packing): elementwise float4 accumulation; the 4 scalar
// fmas are independent -> SLP vectorizer should emit 2x v_pk_fma_f32.
__device__ __forceinline__ void fma4v(float4& acc, const float4 a, const float4 b) {
    acc.x = fmaf(a.x, b.x, acc.x); acc.y = fmaf(a.y, b.y, acc.y);
    acc.z = fmaf(a.z, b.z, acc.z); acc.w = fmaf(a.w, b.w, acc.w);
}
__device__ __forceinline__ float hsum4(const float4 a) {
    return (a.x + a.z) + (a.y + a.w);
}

// ---- Arm B (deterministic packing): inline-asm v_pk_fma_f32 on float2 pairs.
__device__ __forceinline__ void pkfma(float2& acc, const float2 a, const float2 b) {
    asm("v_pk_fma_f32 %0, %1, %2, %0" : "+v"(acc) : "v"(a), "v"(b));
}
__device__ __forceinline__ void pkfma4(float2& acc, const float4 a, const float4 b) {
    pkfma(acc, make_float2(a.x, a.y), make_float2(b.x, b.y));
    pkfma(acc, make_float2(a.z, a.w), make_float2(b.z, b.w));
}

// ---------------- Layer 1: bidirectional, input dim 4 ----------------
// r4-exact structure; dots via fma4v (compiler-pack arm).
__global__ __launch_bounds__(256, 2)
void lstm_layer1(const float* __restrict__ x,      // [B,T,4]
                 const float* __restrict__ Wih_f, const float* __restrict__ Whh_f, const float* __restrict__ b_f,
                 const float* __restrict__ Wih_b, const float* __restrict__ Whh_b, const float* __restrict__ b_b,
                 float* __restrict__ out1)         // [B,T,2H]
{
    const int bidx = blockIdx.x >> 1;
    const int dir  = blockIdx.x & 1;
    const float* __restrict__ Wih = dir ? Wih_b : Wih_f;
    const float* __restrict__ Whh = dir ? Whh_b : Whh_f;
    const float* __restrict__ bb  = dir ? b_b   : b_f;

    const int tid = threadIdx.x;
    const int u   = tid >> 2;
    const int p   = tid & 3;

    __shared__ float xlds[TLEN * 4];    // 32 KB
    __shared__ float hbuf[2][HDIM];

    {   // preload x[b] (2048 float4)
        const float4* src = (const float4*)(x + (size_t)bidx * TLEN * 4);
        float4* dst = (float4*)xlds;
        #pragma unroll
        for (int i = 0; i < 8; ++i) dst[tid + 256 * i] = src[tid + 256 * i];
    }
    if (tid < 2 * HDIM) ((float*)hbuf)[tid] = 0.f;

    // recurrent weights: row gi*64+u, cols [16p,16p+16)
    const float* wbase = Whh + (size_t)u * HDIM + 16 * p;
    const float4 W00 = *(const float4*)(wbase + 0*4096 +  0), W01 = *(const float4*)(wbase + 0*4096 +  4),
                 W02 = *(const float4*)(wbase + 0*4096 +  8), W03 = *(const float4*)(wbase + 0*4096 + 12);
    const float4 W10 = *(const float4*)(wbase + 1*4096 +  0), W11 = *(const float4*)(wbase + 1*4096 +  4),
                 W12 = *(const float4*)(wbase + 1*4096 +  8), W13 = *(const float4*)(wbase + 1*4096 + 12);
    const float4 W20 = *(const float4*)(wbase + 2*4096 +  0), W21 = *(const float4*)(wbase + 2*4096 +  4),
                 W22 = *(const float4*)(wbase + 2*4096 +  8), W23 = *(const float4*)(wbase + 2*4096 + 12);
    const float4 W30 = *(const float4*)(wbase + 3*4096 +  0), W31 = *(const float4*)(wbase + 3*4096 +  4),
                 W32 = *(const float4*)(wbase + 3*4096 +  8), W33 = *(const float4*)(wbase + 3*4096 + 12);
    const float4 I0 = *(const float4*)(Wih + (0*64 + u) * 4);
    const float4 I1 = *(const float4*)(Wih + (1*64 + u) * 4);
    const float4 I2 = *(const float4*)(Wih + (2*64 + u) * 4);
    const float4 I3 = *(const float4*)(Wih + (3*64 + u) * 4);
    const float b0 = bb[u], b1 = bb[64 + u], b2g = bb[128 + u], b3 = bb[192 + u];
    __syncthreads();

    float c = 0.f;
    const float* xp = xlds + (dir ? (TLEN - 1) * 4 : 0);
    const int xstep = dir ? -4 : 4;
    float* outp = out1 + (size_t)bidx * TLEN * (2 * HDIM)
                + (size_t)(dir ? (TLEN - 1) : 0) * (2 * HDIM) + dir * HDIM + u;
    const ptrdiff_t ostep = dir ? -(2 * HDIM) : (2 * HDIM);

    #pragma unroll 2
    for (int s = 0; s < TLEN; ++s) {
        const float* hb = hbuf[s & 1];
        const float4 h0 = *(const float4*)(hb + 16 * p + 0);
        const float4 h1 = *(const float4*)(hb + 16 * p + 4);
        const float4 h2 = *(const float4*)(hb + 16 * p + 8);
        const float4 h3 = *(const float4*)(hb + 16 * p + 12);

        float4 a0 = {0,0,0,0}, a1 = {0,0,0,0}, a2 = {0,0,0,0}, a3 = {0,0,0,0};
        fma4v(a0, W00, h0); fma4v(a0, W01, h1); fma4v(a0, W02, h2); fma4v(a0, W03, h3);
        fma4v(a1, W10, h0); fma4v(a1, W11, h1); fma4v(a1, W12, h2); fma4v(a1, W13, h3);
        fma4v(a2, W20, h0); fma4v(a2, W21, h1); fma4v(a2, W22, h2); fma4v(a2, W23, h3);
        fma4v(a3, W30, h0); fma4v(a3, W31, h1); fma4v(a3, W32, h2); fma4v(a3, W33, h3);
        float g0 = hsum4(a0), g1 = hsum4(a1), g2 = hsum4(a2), g3 = hsum4(a3);

        g0 = dpp_xor2_add(dpp_xor1_add(g0));
        g1 = dpp_xor2_add(dpp_xor1_add(g1));
        g2 = dpp_xor2_add(dpp_xor1_add(g2));
        g3 = dpp_xor2_add(dpp_xor1_add(g3));

        const float4 xv = *(const float4*)xp;
        g0 = dot4(I0, xv, g0 + b0);
        g1 = dot4(I1, xv, g1 + b1);
        g2 = dot4(I2, xv, g2 + b2g);
        g3 = dot4(I3, xv, g3 + b3);

        const float ig = sigmoid_fast(g0);
        const float fg = sigmoid_fast(g1);
        const float gg = tanh_fast(g2);
        const float og = sigmoid_fast(g3);
        c = fmaf(fg, c, ig * gg);
        const float h = og * tanh_fast(c);

        if (p == 0) {
            hbuf[(s & 1) ^ 1][u] = h;
            *outp = h;
        }
        outp += ostep;
        xp   += xstep;
        __syncthreads();
    }
}

// ---------------- Layer 2: unidirectional, input dim 128, + FC ----------------
// r4-exact structure; dots via inline-asm v_pk_fma_f32 (deterministic arm).
__global__ __launch_bounds__(512, 2)
void lstm_layer2(const float* __restrict__ out1,  // [B,T,128]
                 const float* __restrict__ Wih2, const float* __restrict__ Whh2, const float* __restrict__ bias2,
                 const float* __restrict__ Wfc, const float* __restrict__ bfc,
                 float* __restrict__ out)         // [B,1]
{
    const int bidx = blockIdx.x;
    const int tid  = threadIdx.x;
    const int w    = tid >> 6;
    const int lane = tid & 63;
    const int ul   = lane >> 3;
    const int p8   = lane & 7;
    const int u    = w * 8 + ul;
    const int rot  = p8 >> 1;   // bank-conflict-avoiding read rotation

    __shared__ float inbuf[2][CH][2 * HDIM];  // 16 KB
    __shared__ float hbuf[2][HDIM];

    // recurrent weights: row gi*64+u, cols [8p8, 8p8+8)
    const float* whbase = Whh2 + (size_t)u * HDIM + 8 * p8;
    const float4 H00 = *(const float4*)(whbase + 0*4096 + 0), H01 = *(const float4*)(whbase + 0*4096 + 4);
    const float4 H10 = *(const float4*)(whbase + 1*4096 + 0), H11 = *(const float4*)(whbase + 1*4096 + 4);
    const float4 H20 = *(const float4*)(whbase + 2*4096 + 0), H21 = *(const float4*)(whbase + 2*4096 + 4);
    const float4 H30 = *(const float4*)(whbase + 3*4096 + 0), H31 = *(const float4*)(whbase + 3*4096 + 4);
    // input weights: row gi*64+u, cols 16p8 + 4*((j+rot)&3), j=0..3
    const float* wibase = Wih2 + (size_t)u * 128 + 16 * p8;
    #define LWI(g, j) *(const float4*)(wibase + (g)*8192 + ((((j) + rot) & 3) << 2))
    const float4 X00 = LWI(0,0), X01 = LWI(0,1), X02 = LWI(0,2), X03 = LWI(0,3);
    const float4 X10 = LWI(1,0), X11 = LWI(1,1), X12 = LWI(1,2), X13 = LWI(1,3);
    const float4 X20 = LWI(2,0), X21 = LWI(2,1), X22 = LWI(2,2), X23 = LWI(2,3);
    const float4 X30 = LWI(3,0), X31 = LWI(3,1), X32 = LWI(3,2), X33 = LWI(3,3);
    #undef LWI
    const float b0 = bias2[u], b1 = bias2[64 + u], b2g = bias2[128 + u], b3 = bias2[192 + u];

    if (tid < 2 * HDIM) ((float*)hbuf)[tid] = 0.f;

    const float4* src = (const float4*)(out1 + (size_t)bidx * TLEN * (2 * HDIM));
    ((float4*)&inbuf[0][0][0])[tid] = src[tid];   // chunk 0: 512 float4
    __syncthreads();

    float c = 0.f;

    for (int chunk = 0; chunk < TLEN / CH; ++chunk) {
        const int cb = chunk & 1;
        const bool havenext = (chunk + 1 < TLEN / CH);
        float4 pf;
        if (havenext) pf = src[(size_t)(chunk + 1) * 512 + tid];

        #pragma unroll 2
        for (int ts = 0; ts < CH; ++ts) {
            const int s = chunk * CH + ts;
            const float* hb = hbuf[s & 1];
            const float* xr = &inbuf[cb][ts][16 * p8];

            const float4 x0 = *(const float4*)(xr + (((0 + rot) & 3) << 2));
            const float4 x1 = *(const float4*)(xr + (((1 + rot) & 3) << 2));
            const float4 x2 = *(const float4*)(xr + (((2 + rot) & 3) << 2));
            const float4 x3 = *(const float4*)(xr + (((3 + rot) & 3) << 2));
            const float4 h0 = *(const float4*)(hb + 8 * p8 + 0);
            const float4 h1 = *(const float4*)(hb + 8 * p8 + 4);

            float2 a0 = {0,0}, a1 = {0,0}, a2 = {0,0}, a3 = {0,0};
            pkfma4(a0, X00, x0); pkfma4(a0, X01, x1); pkfma4(a0, X02, x2); pkfma4(a0, X03, x3);
            pkfma4(a0, H00, h0); pkfma4(a0, H01, h1);
            pkfma4(a1, X10, x0); pkfma4(a1, X11, x1); pkfma4(a1, X12, x2); pkfma4(a1, X13, x3);
            pkfma4(a1, H10, h0); pkfma4(a1, H11, h1);
            pkfma4(a2, X20, x0); pkfma4(a2, X21, x1); pkfma4(a2, X22, x2); pkfma4(a2, X23, x3);
            pkfma4(a2, H20, h0); pkfma4(a2, H21, h1);
            pkfma4(a3, X30, x0); pkfma4(a3, X31, x1); pkfma4(a3, X32, x2); pkfma4(a3, X33, x3);
            pkfma4(a3, H30, h0); pkfma4(a3, H31, h1);
            float g0 = a0.x + a0.y, g1 = a1.x + a1.y, g2 = a2.x + a2.y, g3 = a3.x + a3.y;

            g0 = swz_xor4_add(dpp_xor2_add(dpp_xor1_add(g0))) + b0;
            g1 = swz_xor4_add(dpp_xor2_add(dpp_xor1_add(g1))) + b1;
            g2 = swz_xor4_add(dpp_xor2_add(dpp_xor1_add(g2))) + b2g;
            g3 = swz_xor4_add(dpp_xor2_add(dpp_xor1_add(g3))) + b3;

            const float ig = sigmoid_fast(g0);
            const float fg = sigmoid_fast(g1);
            const float gg = tanh_fast(g2);
            const float og = sigmoid_fast(g3);
            c = fmaf(fg, c, ig * gg);
            const float h = og * tanh_fast(c);

            if (p8 == 0) hbuf[(s & 1) ^ 1][u] = h;
            __syncthreads();
        }
        if (havenext) {
            ((float4*)&inbuf[cb ^ 1][0][0])[tid] = pf;
            __syncthreads();
        }
    }

    // final h (T even) is in hbuf[0]; FC
    if (w == 0) {
        float part = hbuf[0][lane] * Wfc[lane];
        #pragma unroll
        for (int m = 1; m < 64; m <<= 1) part += __shfl_xor(part, m, 64);
        if (lane == 0) out[bidx] = part + bfc[0];
    }
}

extern "C" void kernel_launch(void* const* d_in, const int* in_sizes, int n_in,
                              void* d_out, int out_size, void* d_ws, size_t ws_size,
                              hipStream_t stream) {
    const float* x     = (const float*)d_in[0];
    const float* Wih_f = (const float*)d_in[1];
    const float* Whh_f = (const float*)d_in[2];
    const float* b_f   = (const float*)d_in[3];
    const float* Wih_b = (const float*)d_in[4];
    const float* Whh_b = (const float*)d_in[5];
    const float* b_b   = (const float*)d_in[6];
    const float* Wih2  = (const float*)d_in[7];
    const float* Whh2  = (const float*)d_in[8];
    const float* b2    = (const float*)d_in[9];
    const float* Wfc   = (const float*)d_in[10];
    const float* bfc   = (const float*)d_in[11];

    float* out1 = (float*)d_ws;  // [B,T,2H] fp32 (268 MB workspace; proven available)

    lstm_layer1<<<dim3(2 * BATCH), dim3(256), 0, stream>>>(
        x, Wih_f, Whh_f, b_f, Wih_b, Whh_b, b_b, out1);
    lstm_layer2<<<dim3(BATCH), dim3(512), 0, stream>>>(
        out1, Wih2, Whh2, b2, Wfc, bfc, (float*)d_out);
}

// Round 8
// 2191.116 us; speedup vs baseline: 1.2211x; 1.0828x over previous
//
#include <hip/hip_runtime.h>

#define HDIM 64
#define BATCH 256
#define TLEN 2048
#define CH 16   // layer-2 streaming chunk (steps)

typedef float v2f __attribute__((ext_vector_type(2)));

__device__ __forceinline__ float rcp_fast(float x) { return __builtin_amdgcn_rcpf(x); }
__device__ __forceinline__ float sigmoid_fast(float x) { return rcp_fast(1.0f + __expf(-x)); }
__device__ __forceinline__ float tanh_fast(float x)    { return 1.0f - 2.0f * rcp_fast(1.0f + __expf(2.0f * x)); }

// quad_perm DPP adds: lane^1 and lane^2 (VALU, no LDS pipe) — r2-r4 proven
__device__ __forceinline__ float dpp_xor1_add(float x) {
    int v = __builtin_amdgcn_update_dpp(0, __float_as_int(x), 0xB1, 0xF, 0xF, true);
    return x + __int_as_float(v);
}
__device__ __forceinline__ float dpp_xor2_add(float x) {
    int v = __builtin_amdgcn_update_dpp(0, __float_as_int(x), 0x4E, 0xF, 0xF, true);
    return x + __int_as_float(v);
}
__device__ __forceinline__ float swz_xor4_add(float x) {
    int v = __builtin_amdgcn_ds_swizzle(__float_as_int(x), 0x101F); // xor-4 butterfly
    return x + __int_as_float(v);
}

// Packed dual-FMA via native <2 x float>: lowers to v_pk_fma_f32 through ISel
// (packed-FP32 subtarget) with no inline-asm constraints to perturb the LDS
// codegen (r7's asm arm regressed exactly there).
__device__ __forceinline__ void pk2(v2f& acc, float ax, float ay, float bx, float by) {
    v2f a = {ax, ay}, b = {bx, by};
    acc = __builtin_elementwise_fma(a, b, acc);
}
__device__ __forceinline__ void pk4(v2f& acc, const float4 a, const float4 b) {
    pk2(acc, a.x, a.y, b.x, b.y);
    pk2(acc, a.z, a.w, b.z, b.w);
}

// ---------------- Layer 1: bidirectional, input dim 4 ----------------
// r4-exact structure; dots via packed v2f FMA.
__global__ __launch_bounds__(256, 2)
void lstm_layer1(const float* __restrict__ x,      // [B,T,4]
                 const float* __restrict__ Wih_f, const float* __restrict__ Whh_f, const float* __restrict__ b_f,
                 const float* __restrict__ Wih_b, const float* __restrict__ Whh_b, const float* __restrict__ b_b,
                 float* __restrict__ out1)         // [B,T,2H]
{
    const int bidx = blockIdx.x >> 1;
    const int dir  = blockIdx.x & 1;
    const float* __restrict__ Wih = dir ? Wih_b : Wih_f;
    const float* __restrict__ Whh = dir ? Whh_b : Whh_f;
    const float* __restrict__ bb  = dir ? b_b   : b_f;

    const int tid = threadIdx.x;
    const int u   = tid >> 2;
    const int p   = tid & 3;

    __shared__ float xlds[TLEN * 4];    // 32 KB
    __shared__ float hbuf[2][HDIM];

    {   // preload x[b] (2048 float4)
        const float4* src = (const float4*)(x + (size_t)bidx * TLEN * 4);
        float4* dst = (float4*)xlds;
        #pragma unroll
        for (int i = 0; i < 8; ++i) dst[tid + 256 * i] = src[tid + 256 * i];
    }
    if (tid < 2 * HDIM) ((float*)hbuf)[tid] = 0.f;

    // recurrent weights: row gi*64+u, cols [16p,16p+16)
    const float* wbase = Whh + (size_t)u * HDIM + 16 * p;
    const float4 W00 = *(const float4*)(wbase + 0*4096 +  0), W01 = *(const float4*)(wbase + 0*4096 +  4),
                 W02 = *(const float4*)(wbase + 0*4096 +  8), W03 = *(const float4*)(wbase + 0*4096 + 12);
    const float4 W10 = *(const float4*)(wbase + 1*4096 +  0), W11 = *(const float4*)(wbase + 1*4096 +  4),
                 W12 = *(const float4*)(wbase + 1*4096 +  8), W13 = *(const float4*)(wbase + 1*4096 + 12);
    const float4 W20 = *(const float4*)(wbase + 2*4096 +  0), W21 = *(const float4*)(wbase + 2*4096 +  4),
                 W22 = *(const float4*)(wbase + 2*4096 +  8), W23 = *(const float4*)(wbase + 2*4096 + 12);
    const float4 W30 = *(const float4*)(wbase + 3*4096 +  0), W31 = *(const float4*)(wbase + 3*4096 +  4),
                 W32 = *(const float4*)(wbase + 3*4096 +  8), W33 = *(const float4*)(wbase + 3*4096 + 12);
    const float4 I0 = *(const float4*)(Wih + (0*64 + u) * 4);
    const float4 I1 = *(const float4*)(Wih + (1*64 + u) * 4);
    const float4 I2 = *(const float4*)(Wih + (2*64 + u) * 4);
    const float4 I3 = *(const float4*)(Wih + (3*64 + u) * 4);
    const float b0 = bb[u], b1 = bb[64 + u], b2g = bb[128 + u], b3 = bb[192 + u];
    __syncthreads();

    float c = 0.f;
    const float* xp = xlds + (dir ? (TLEN - 1) * 4 : 0);
    const int xstep = dir ? -4 : 4;
    float* outp = out1 + (size_t)bidx * TLEN * (2 * HDIM)
                + (size_t)(dir ? (TLEN - 1) : 0) * (2 * HDIM) + dir * HDIM + u;
    const ptrdiff_t ostep = dir ? -(2 * HDIM) : (2 * HDIM);

    #pragma unroll 2
    for (int s = 0; s < TLEN; ++s) {
        const float* hb = hbuf[s & 1];
        const float4 h0 = *(const float4*)(hb + 16 * p + 0);
        const float4 h1 = *(const float4*)(hb + 16 * p + 4);
        const float4 h2 = *(const float4*)(hb + 16 * p + 8);
        const float4 h3 = *(const float4*)(hb + 16 * p + 12);

        v2f a0 = {0.f, 0.f}, a1 = {0.f, 0.f}, a2 = {0.f, 0.f}, a3 = {0.f, 0.f};
        pk4(a0, W00, h0); pk4(a0, W01, h1); pk4(a0, W02, h2); pk4(a0, W03, h3);
        pk4(a1, W10, h0); pk4(a1, W11, h1); pk4(a1, W12, h2); pk4(a1, W13, h3);
        pk4(a2, W20, h0); pk4(a2, W21, h1); pk4(a2, W22, h2); pk4(a2, W23, h3);
        pk4(a3, W30, h0); pk4(a3, W31, h1); pk4(a3, W32, h2); pk4(a3, W33, h3);
        float g0 = a0.x + a0.y, g1 = a1.x + a1.y, g2 = a2.x + a2.y, g3 = a3.x + a3.y;

        g0 = dpp_xor2_add(dpp_xor1_add(g0));
        g1 = dpp_xor2_add(dpp_xor1_add(g1));
        g2 = dpp_xor2_add(dpp_xor1_add(g2));
        g3 = dpp_xor2_add(dpp_xor1_add(g3));

        // x-projection + bias added exactly once, after the quad reduce
        const float4 xv = *(const float4*)xp;
        v2f e0 = {g0 + b0, 0.f}, e1 = {g1 + b1, 0.f}, e2 = {g2 + b2g, 0.f}, e3 = {g3 + b3, 0.f};
        pk4(e0, I0, xv); pk4(e1, I1, xv); pk4(e2, I2, xv); pk4(e3, I3, xv);
        g0 = e0.x + e0.y; g1 = e1.x + e1.y; g2 = e2.x + e2.y; g3 = e3.x + e3.y;

        const float ig = sigmoid_fast(g0);
        const float fg = sigmoid_fast(g1);
        const float gg = tanh_fast(g2);
        const float og = sigmoid_fast(g3);
        c = fmaf(fg, c, ig * gg);
        const float h = og * tanh_fast(c);

        if (p == 0) {
            hbuf[(s & 1) ^ 1][u] = h;
            *outp = h;
        }
        outp += ostep;
        xp   += xstep;
        __syncthreads();
    }
}

// ---------------- Layer 2: unidirectional, input dim 128, + FC ----------------
// r4-exact structure; dots via packed v2f FMA.
__global__ __launch_bounds__(512, 2)
void lstm_layer2(const float* __restrict__ out1,  // [B,T,128]
                 const float* __restrict__ Wih2, const float* __restrict__ Whh2, const float* __restrict__ bias2,
                 const float* __restrict__ Wfc, const float* __restrict__ bfc,
                 float* __restrict__ out)         // [B,1]
{
    const int bidx = blockIdx.x;
    const int tid  = threadIdx.x;
    const int w    = tid >> 6;
    const int lane = tid & 63;
    const int ul   = lane >> 3;
    const int p8   = lane & 7;
    const int u    = w * 8 + ul;
    const int rot  = p8 >> 1;   // bank-conflict-avoiding read rotation

    __shared__ float inbuf[2][CH][2 * HDIM];  // 16 KB
    __shared__ float hbuf[2][HDIM];

    // recurrent weights: row gi*64+u, cols [8p8, 8p8+8)
    const float* whbase = Whh2 + (size_t)u * HDIM + 8 * p8;
    const float4 H00 = *(const float4*)(whbase + 0*4096 + 0), H01 = *(const float4*)(whbase + 0*4096 + 4);
    const float4 H10 = *(const float4*)(whbase + 1*4096 + 0), H11 = *(const float4*)(whbase + 1*4096 + 4);
    const float4 H20 = *(const float4*)(whbase + 2*4096 + 0), H21 = *(const float4*)(whbase + 2*4096 + 4);
    const float4 H30 = *(const float4*)(whbase + 3*4096 + 0), H31 = *(const float4*)(whbase + 3*4096 + 4);
    // input weights: row gi*64+u, cols 16p8 + 4*((j+rot)&3), j=0..3
    const float* wibase = Wih2 + (size_t)u * 128 + 16 * p8;
    #define LWI(g, j) *(const float4*)(wibase + (g)*8192 + ((((j) + rot) & 3) << 2))
    const float4 X00 = LWI(0,0), X01 = LWI(0,1), X02 = LWI(0,2), X03 = LWI(0,3);
    const float4 X10 = LWI(1,0), X11 = LWI(1,1), X12 = LWI(1,2), X13 = LWI(1,3);
    const float4 X20 = LWI(2,0), X21 = LWI(2,1), X22 = LWI(2,2), X23 = LWI(2,3);
    const float4 X30 = LWI(3,0), X31 = LWI(3,1), X32 = LWI(3,2), X33 = LWI(3,3);
    #undef LWI
    const float b0 = bias2[u], b1 = bias2[64 + u], b2g = bias2[128 + u], b3 = bias2[192 + u];

    if (tid < 2 * HDIM) ((float*)hbuf)[tid] = 0.f;

    const float4* src = (const float4*)(out1 + (size_t)bidx * TLEN * (2 * HDIM));
    ((float4*)&inbuf[0][0][0])[tid] = src[tid];   // chunk 0: 512 float4
    __syncthreads();

    float c = 0.f;

    for (int chunk = 0; chunk < TLEN / CH; ++chunk) {
        const int cb = chunk & 1;
        const bool havenext = (chunk + 1 < TLEN / CH);
        float4 pf;
        if (havenext) pf = src[(size_t)(chunk + 1) * 512 + tid];

        #pragma unroll 2
        for (int ts = 0; ts < CH; ++ts) {
            const int s = chunk * CH + ts;
            const float* hb = hbuf[s & 1];
            const float* xr = &inbuf[cb][ts][16 * p8];

            const float4 x0 = *(const float4*)(xr + (((0 + rot) & 3) << 2));
            const float4 x1 = *(const float4*)(xr + (((1 + rot) & 3) << 2));
            const float4 x2 = *(const float4*)(xr + (((2 + rot) & 3) << 2));
            const float4 x3 = *(const float4*)(xr + (((3 + rot) & 3) << 2));
            const float4 h0 = *(const float4*)(hb + 8 * p8 + 0);
            const float4 h1 = *(const float4*)(hb + 8 * p8 + 4);

            v2f a0 = {0.f, 0.f}, a1 = {0.f, 0.f}, a2 = {0.f, 0.f}, a3 = {0.f, 0.f};
            pk4(a0, X00, x0); pk4(a0, X01, x1); pk4(a0, X02, x2); pk4(a0, X03, x3);
            pk4(a0, H00, h0); pk4(a0, H01, h1);
            pk4(a1, X10, x0); pk4(a1, X11, x1); pk4(a1, X12, x2); pk4(a1, X13, x3);
            pk4(a1, H10, h0); pk4(a1, H11, h1);
            pk4(a2, X20, x0); pk4(a2, X21, x1); pk4(a2, X22, x2); pk4(a2, X23, x3);
            pk4(a2, H20, h0); pk4(a2, H21, h1);
            pk4(a3, X30, x0); pk4(a3, X31, x1); pk4(a3, X32, x2); pk4(a3, X33, x3);
            pk4(a3, H30, h0); pk4(a3, H31, h1);
            float g0 = a0.x + a0.y, g1 = a1.x + a1.y, g2 = a2.x + a2.y, g3 = a3.x + a3.y;

            g0 = swz_xor4_add(dpp_xor2_add(dpp_xor1_add(g0))) + b0;
            g1 = swz_xor4_add(dpp_xor2_add(dpp_xor1_add(g1))) + b1;
            g2 = swz_xor4_add(dpp_xor2_add(dpp_xor1_add(g2))) + b2g;
            g3 = swz_xor4_add(dpp_xor2_add(dpp_xor1_add(g3))) + b3;

            const float ig = sigmoid_fast(g0);
            const float fg = sigmoid_fast(g1);
            const float gg = tanh_fast(g2);
            const float og = sigmoid_fast(g3);
            c = fmaf(fg, c, ig * gg);
            const float h = og * tanh_fast(c);

            if (p8 == 0) hbuf[(s & 1) ^ 1][u] = h;
            __syncthreads();
        }
        if (havenext) {
            ((float4*)&inbuf[cb ^ 1][0][0])[tid] = pf;
            __syncthreads();
        }
    }

    // final h (T even) is in hbuf[0]; FC
    if (w == 0) {
        float part = hbuf[0][lane] * Wfc[lane];
        #pragma unroll
        for (int m = 1; m < 64; m <<= 1) part += __shfl_xor(part, m, 64);
        if (lane == 0) out[bidx] = part + bfc[0];
    }
}

extern "C" void kernel_launch(void* const* d_in, const int* in_sizes, int n_in,
                              void* d_out, int out_size, void* d_ws, size_t ws_size,
                              hipStream_t stream) {
    const float* x     = (const float*)d_in[0];
    const float* Wih_f = (const float*)d_in[1];
    const float* Whh_f = (const float*)d_in[2];
    const float* b_f   = (const float*)d_in[3];
    const float* Wih_b = (const float*)d_in[4];
    const float* Whh_b = (const float*)d_in[5];
    const float* b_b   = (const float*)d_in[6];
    const float* Wih2  = (const float*)d_in[7];
    const float* Whh2  = (const float*)d_in[8];
    const float* b2    = (const float*)d_in[9];
    const float* Wfc   = (const float*)d_in[10];
    const float* bfc   = (const float*)d_in[11];

    float* out1 = (float*)d_ws;  // [B,T,2H] fp32 (268 MB workspace; proven available)

    lstm_layer1<<<dim3(2 * BATCH), dim3(256), 0, stream>>>(
        x, Wih_f, Whh_f, b_f, Wih_b, Whh_b, b_b, out1);
    lstm_layer2<<<dim3(BATCH), dim3(512), 0, stream>>>(
        out1, Wih2, Whh2, b2, Wfc, bfc, (float*)d_out);
}